// Round 2
// baseline (1500.776 us; speedup 1.0000x reference)
//
#include <hip/hip_runtime.h>

typedef unsigned short u16;
typedef u16 u16x8 __attribute__((ext_vector_type(8)));
typedef u16 u16x4 __attribute__((ext_vector_type(4)));
typedef float f32x4 __attribute__((ext_vector_type(4)));

__device__ __forceinline__ float b2f(u16 u) {
  union { unsigned int i; float f; } v;
  v.i = ((unsigned int)u) << 16;
  return v.f;
}
__device__ __forceinline__ u16 f2b(float f) {
  union { float f; unsigned int i; } v;
  v.f = f;
  unsigned int r = v.i + 0x7fffu + ((v.i >> 16) & 1u);
  return (u16)(r >> 16);
}

// ---------------- LayerNorm: fp32 in, bf16 out. One wave per 512-elem row ----------------
__global__ __launch_bounds__(256) void ln_kernel(const float* __restrict__ inv,
                                                 const float* __restrict__ w,
                                                 const float* __restrict__ bvec,
                                                 u16* __restrict__ out) {
  const int row = blockIdx.x * 4 + (threadIdx.x >> 6);
  const int lane = threadIdx.x & 63;
  const float* p = inv + (size_t)row * 512 + lane * 8;
  f32x4 v0 = *(const f32x4*)p;
  f32x4 v1 = *(const f32x4*)(p + 4);
  float x[8];
#pragma unroll
  for (int i = 0; i < 4; i++) { x[i] = v0[i]; x[4 + i] = v1[i]; }
  float s = 0.f;
#pragma unroll
  for (int i = 0; i < 8; i++) s += x[i];
#pragma unroll
  for (int m = 1; m < 64; m <<= 1) s += __shfl_xor(s, m, 64);
  const float mu = s * (1.0f / 512.0f);
  float vs = 0.f;
#pragma unroll
  for (int i = 0; i < 8; i++) { const float d = x[i] - mu; vs += d * d; }
#pragma unroll
  for (int m = 1; m < 64; m <<= 1) vs += __shfl_xor(vs, m, 64);
  const float r = rsqrtf(vs * (1.0f / 512.0f) + 1e-5f);
  const f32x4 w0 = *(const f32x4*)(w + lane * 8);
  const f32x4 w1 = *(const f32x4*)(w + lane * 8 + 4);
  const f32x4 b0 = *(const f32x4*)(bvec + lane * 8);
  const f32x4 b1 = *(const f32x4*)(bvec + lane * 8 + 4);
  u16x8 ov;
#pragma unroll
  for (int i = 0; i < 4; i++) {
    ov[i] = f2b((x[i] - mu) * r * w0[i] + b0[i]);
    ov[4 + i] = f2b((x[4 + i] - mu) * r * w1[i] + b1[i]);
  }
  *(u16x8*)(out + (size_t)row * 512 + lane * 8) = ov;
}

// ---------------- GEMM: C[M,N] = A[M,K](bf16) @ B[K,N](fp32), fp32 accum ----------------
// 128x128 tile, BK=32, 256 threads, 8x8 micro-tile.
enum { EPI_NONE = 0, EPI_F32RES = 1, EPI_GELU = 2 };

template<int EPI>
__global__ __launch_bounds__(256) void gemm_kernel(
    const u16* __restrict__ A, const float* __restrict__ B,
    int M, int N, int K,
    u16* __restrict__ Cb,           // bf16 out (NONE/GELU)
    float* __restrict__ Cf,         // fp32 out (F32RES)
    const float* __restrict__ bias, // fp32 bias (F32RES/GELU)
    const float* __restrict__ resf) // fp32 residual (F32RES)
{
  __shared__ float At[32][132]; // [k][m]
  __shared__ float Bs[32][132]; // [k][n]
  const int tid = threadIdx.x;
  const int m0 = blockIdx.y * 128, n0 = blockIdx.x * 128;
  const int ty = tid >> 4, tx = tid & 15;
  const int am = tid >> 1, ak = (tid & 1) << 4;
  const int bk = tid >> 3, bn = (tid & 7) << 4;
  float acc[8][8];
#pragma unroll
  for (int i = 0; i < 8; i++)
#pragma unroll
    for (int j = 0; j < 8; j++) acc[i][j] = 0.f;
  const u16* Ap = A + (size_t)(m0 + am) * K + ak;
  const float* Bp = B + (size_t)bk * N + n0 + bn;
  for (int k0 = 0; k0 < K; k0 += 32) {
    const u16x8 a0 = *(const u16x8*)(Ap);
    const u16x8 a1 = *(const u16x8*)(Ap + 8);
    const f32x4 bv0 = *(const f32x4*)(Bp);
    const f32x4 bv1 = *(const f32x4*)(Bp + 4);
    const f32x4 bv2 = *(const f32x4*)(Bp + 8);
    const f32x4 bv3 = *(const f32x4*)(Bp + 12);
    Ap += 32;
    Bp += (size_t)32 * N;
    __syncthreads();
#pragma unroll
    for (int i = 0; i < 8; i++) {
      At[ak + i][am] = b2f(a0[i]);
      At[ak + 8 + i][am] = b2f(a1[i]);
    }
#pragma unroll
    for (int i = 0; i < 4; i++) {
      Bs[bk][bn + i] = bv0[i];
      Bs[bk][bn + 4 + i] = bv1[i];
      Bs[bk][bn + 8 + i] = bv2[i];
      Bs[bk][bn + 12 + i] = bv3[i];
    }
    __syncthreads();
#pragma unroll 4
    for (int kk = 0; kk < 32; kk++) {
      const f32x4 a_0 = *(const f32x4*)&At[kk][ty * 8];
      const f32x4 a_1 = *(const f32x4*)&At[kk][ty * 8 + 4];
      const f32x4 b_0 = *(const f32x4*)&Bs[kk][tx * 4];
      const f32x4 b_1 = *(const f32x4*)&Bs[kk][64 + tx * 4];
      float aa[8], bb[8];
#pragma unroll
      for (int i = 0; i < 4; i++) {
        aa[i] = a_0[i]; aa[4 + i] = a_1[i];
        bb[i] = b_0[i]; bb[4 + i] = b_1[i];
      }
#pragma unroll
      for (int i = 0; i < 8; i++)
#pragma unroll
        for (int j = 0; j < 8; j++)
          acc[i][j] = fmaf(aa[i], bb[j], acc[i][j]);
    }
  }
  const int c0 = n0 + tx * 4, c1 = n0 + 64 + tx * 4;
  float bcol[8];
#pragma unroll
  for (int j = 0; j < 8; j++) bcol[j] = 0.f;
  if (EPI != EPI_NONE) {
    const f32x4 bv0 = *(const f32x4*)(bias + c0);
    const f32x4 bv1 = *(const f32x4*)(bias + c1);
#pragma unroll
    for (int j = 0; j < 4; j++) { bcol[j] = bv0[j]; bcol[4 + j] = bv1[j]; }
  }
#pragma unroll
  for (int i = 0; i < 8; i++) {
    const int m = m0 + ty * 8 + i;
    const size_t rbase = (size_t)m * N;
    float v[8];
#pragma unroll
    for (int j = 0; j < 8; j++) v[j] = acc[i][j] + bcol[j];
    if (EPI == EPI_F32RES) {
      const f32x4 r0 = *(const f32x4*)(resf + rbase + c0);
      const f32x4 r1 = *(const f32x4*)(resf + rbase + c1);
      f32x4 o0, o1;
#pragma unroll
      for (int j = 0; j < 4; j++) { o0[j] = v[j] + r0[j]; o1[j] = v[4 + j] + r1[j]; }
      *(f32x4*)(Cf + rbase + c0) = o0;
      *(f32x4*)(Cf + rbase + c1) = o1;
    } else {
      if (EPI == EPI_GELU) {
#pragma unroll
        for (int j = 0; j < 8; j++)
          v[j] = 0.5f * v[j] * (1.0f + erff(v[j] * 0.70710678118654752f));
      }
      u16x4 s0, s1;
#pragma unroll
      for (int j = 0; j < 4; j++) { s0[j] = f2b(v[j]); s1[j] = f2b(v[4 + j]); }
      *(u16x4*)(Cb + rbase + c0) = s0;
      *(u16x4*)(Cb + rbase + c1) = s1;
    }
  }
}

// ---------------- Flash attention (vector fp32), 64 q-rows per block ----------------
__global__ __launch_bounds__(256) void attn_kernel(const u16* __restrict__ qkv,
                                                   const u16* __restrict__ sb,
                                                   u16* __restrict__ ob) {
  __shared__ float QT[64][68];  // [d][q], scaled by 1/8
  __shared__ u16 KST[64][72];   // [d][k] bf16 of (k+s)
  __shared__ u16 Vs[64][72];    // [k][d]
  __shared__ u16 PT[64][72];    // [k][q]
  __shared__ float red[4][64];
  __shared__ float m_l[64], l_l[64], al_l[64];
  const int tid = threadIdx.x;
  const int wv = tid >> 6, lane = tid & 63;
  const int ty = tid >> 4, tx = tid & 15;
  const int q0 = blockIdx.x * 64;
  const int b = blockIdx.y >> 3, h = blockIdx.y & 7;
  const size_t rb = (size_t)b * 2048;
  const int lr = tid >> 2;
  const int lc = (tid & 3) << 4;

  if (tid < 64) { m_l[tid] = -1e30f; l_l[tid] = 0.f; }
  {
    const u16* p = qkv + (rb + q0 + lr) * 1536 + h * 64 + lc;
    const u16x8 v0 = *(const u16x8*)p;
    const u16x8 v1 = *(const u16x8*)(p + 8);
#pragma unroll
    for (int i = 0; i < 8; i++) {
      QT[lc + i][lr] = b2f(v0[i]) * 0.125f;
      QT[lc + 8 + i][lr] = b2f(v1[i]) * 0.125f;
    }
  }
  float oacc[4][4];
#pragma unroll
  for (int i = 0; i < 4; i++)
#pragma unroll
    for (int j = 0; j < 4; j++) oacc[i][j] = 0.f;
  __syncthreads();

  for (int k0 = 0; k0 < 2048; k0 += 64) {
    {
      const u16* pk = qkv + (rb + k0 + lr) * 1536 + 512 + h * 64 + lc;
      const u16* ps = sb + (rb + k0 + lr) * 512 + h * 64 + lc;
      const u16x8 kv0 = *(const u16x8*)pk;
      const u16x8 kv1 = *(const u16x8*)(pk + 8);
      const u16x8 sv0 = *(const u16x8*)ps;
      const u16x8 sv1 = *(const u16x8*)(ps + 8);
      const u16x8 vv0 = *(const u16x8*)(pk + 512);
      const u16x8 vv1 = *(const u16x8*)(pk + 520);
#pragma unroll
      for (int i = 0; i < 8; i++) {
        KST[lc + i][lr] = f2b(b2f(kv0[i]) + b2f(sv0[i]));
        KST[lc + 8 + i][lr] = f2b(b2f(kv1[i]) + b2f(sv1[i]));
      }
      *(u16x8*)&Vs[lr][lc] = vv0;
      *(u16x8*)&Vs[lr][lc + 8] = vv1;
    }
    __syncthreads();
    // S[q][k] = sum_d Q[q][d]*KS[k][d]  (q = ty*4+i, k = tx*4+j)
    float sa[4][4];
#pragma unroll
    for (int i = 0; i < 4; i++)
#pragma unroll
      for (int j = 0; j < 4; j++) sa[i][j] = 0.f;
#pragma unroll 4
    for (int d = 0; d < 64; d++) {
      const f32x4 aq = *(const f32x4*)&QT[d][ty * 4];
      const u16x4 bk4 = *(const u16x4*)&KST[d][tx * 4];
      float bf[4];
#pragma unroll
      for (int j = 0; j < 4; j++) bf[j] = b2f(bk4[j]);
#pragma unroll
      for (int i = 0; i < 4; i++)
#pragma unroll
        for (int j = 0; j < 4; j++)
          sa[i][j] = fmaf(aq[i], bf[j], sa[i][j]);
    }
#pragma unroll
    for (int j = 0; j < 4; j++) {
      u16x4 col;
#pragma unroll
      for (int i = 0; i < 4; i++) col[i] = f2b(sa[i][j]);
      *(u16x4*)&PT[tx * 4 + j][ty * 4] = col;
    }
    __syncthreads();
    float pm = -1e30f;
#pragma unroll
    for (int jj = 0; jj < 16; jj++) pm = fmaxf(pm, b2f(PT[wv * 16 + jj][lane]));
    red[wv][lane] = pm;
    __syncthreads();
    if (wv == 0) {
      const float mt = fmaxf(fmaxf(red[0][lane], red[1][lane]),
                             fmaxf(red[2][lane], red[3][lane]));
      const float mo = m_l[lane];
      const float mn = fmaxf(mo, mt);
      m_l[lane] = mn;
      al_l[lane] = __expf(mo - mn);
    }
    __syncthreads();
    const float mn = m_l[lane];
    float psum = 0.f;
#pragma unroll
    for (int jj = 0; jj < 16; jj++) {
      const int j = wv * 16 + jj;
      const u16 eb = f2b(__expf(b2f(PT[j][lane]) - mn));
      PT[j][lane] = eb;
      psum += b2f(eb);
    }
    red[wv][lane] = psum;
    __syncthreads();
    if (wv == 0)
      l_l[lane] = l_l[lane] * al_l[lane] + red[0][lane] + red[1][lane] +
                  red[2][lane] + red[3][lane];
    float af[4];
#pragma unroll
    for (int i = 0; i < 4; i++) af[i] = al_l[ty * 4 + i];
#pragma unroll
    for (int i = 0; i < 4; i++)
#pragma unroll
      for (int j = 0; j < 4; j++) oacc[i][j] *= af[i];
#pragma unroll 4
    for (int k = 0; k < 64; k++) {
      const u16x4 ap4 = *(const u16x4*)&PT[k][ty * 4];
      const u16x4 vv4 = *(const u16x4*)&Vs[k][tx * 4];
#pragma unroll
      for (int i = 0; i < 4; i++)
#pragma unroll
        for (int j = 0; j < 4; j++)
          oacc[i][j] = fmaf(b2f(ap4[i]), b2f(vv4[j]), oacc[i][j]);
    }
    __syncthreads();
  }
#pragma unroll
  for (int i = 0; i < 4; i++) {
    const float rinv = 1.0f / l_l[ty * 4 + i];
    u16x4 ov;
#pragma unroll
    for (int j = 0; j < 4; j++) ov[j] = f2b(oacc[i][j] * rinv);
    *(u16x4*)(ob + (rb + q0 + ty * 4 + i) * 512 + h * 64 + tx * 4) = ov;
  }
}

// ---------------- elementwise o*gate (bf16) ----------------
__global__ __launch_bounds__(256) void ew_mul_kernel(const u16* __restrict__ a,
                                                     const u16* __restrict__ b,
                                                     u16* __restrict__ o) {
  const size_t idx = ((size_t)blockIdx.x * 256 + threadIdx.x) * 8;
  const u16x8 av = *(const u16x8*)(a + idx);
  const u16x8 bv = *(const u16x8*)(b + idx);
  u16x8 ov;
#pragma unroll
  for (int i = 0; i < 8; i++) ov[i] = f2b(b2f(av[i]) * b2f(bv[i]));
  *(u16x8*)(o + idx) = ov;
}

extern "C" void kernel_launch(void* const* d_in, const int* in_sizes, int n_in,
                              void* d_out, int out_size, void* d_ws, size_t ws_size,
                              hipStream_t stream) {
  const float* x      = (const float*)d_in[0];
  const float* e      = (const float*)d_in[1];
  const float* w_qkv  = (const float*)d_in[2];
  const float* w_s    = (const float*)d_in[3];
  const float* w_gate = (const float*)d_in[4];
  const float* w_proj = (const float*)d_in[5];
  const float* b_proj = (const float*)d_in[6];
  const float* ln1w   = (const float*)d_in[7];
  const float* ln1b   = (const float*)d_in[8];
  const float* ln2w   = (const float*)d_in[9];
  const float* ln2b   = (const float*)d_in[10];
  const float* ln3w   = (const float*)d_in[11];
  const float* ln3b   = (const float*)d_in[12];
  const float* w_fc1  = (const float*)d_in[13];
  const float* b_fc1  = (const float*)d_in[14];
  const float* w_fc2  = (const float*)d_in[15];
  const float* b_fc2  = (const float*)d_in[16];
  float* out = (float*)d_out;
  char* ws = (char*)d_ws;

  // workspace layout (80 MiB peak, with aliasing); intermediates bf16, x1 fp32
  u16* xn   = (u16*)(ws + 0);          // 8 MiB, reused as xn3
  u16* en   = (u16*)(ws + 8388608);    // 8 MiB, reused as og
  u16* qkv  = (u16*)(ws + 16777216);   // 24 MiB, later h spans qkv+s (32 MiB)
  u16* sbuf = (u16*)(ws + 41943040);   // 8 MiB
  u16* gate = (u16*)(ws + 50331648);   // 8 MiB
  u16* obuf = (u16*)(ws + 58720256);   // 8 MiB
  float* x1 = (float*)(ws + 67108864); // 16 MiB fp32
  u16* og   = en;
  u16* hbuf = qkv;
  u16* xn3  = xn;

  dim3 blk(256);
  ln_kernel<<<2048, blk, 0, stream>>>(x, ln1w, ln1b, xn);
  ln_kernel<<<2048, blk, 0, stream>>>(e, ln2w, ln2b, en);
  gemm_kernel<EPI_NONE><<<dim3(12, 64), blk, 0, stream>>>(
      xn, w_qkv, 8192, 1536, 512, qkv, nullptr, nullptr, nullptr);
  gemm_kernel<EPI_NONE><<<dim3(4, 64), blk, 0, stream>>>(
      en, w_s, 8192, 512, 512, sbuf, nullptr, nullptr, nullptr);
  gemm_kernel<EPI_NONE><<<dim3(4, 64), blk, 0, stream>>>(
      xn, w_gate, 8192, 512, 512, gate, nullptr, nullptr, nullptr);
  attn_kernel<<<dim3(32, 32), blk, 0, stream>>>(qkv, sbuf, obuf);
  ew_mul_kernel<<<2048, blk, 0, stream>>>(obuf, gate, og);
  gemm_kernel<EPI_F32RES><<<dim3(4, 64), blk, 0, stream>>>(
      og, w_proj, 8192, 512, 512, nullptr, x1, b_proj, x);
  ln_kernel<<<2048, blk, 0, stream>>>(x1, ln3w, ln3b, xn3);
  gemm_kernel<EPI_GELU><<<dim3(16, 64), blk, 0, stream>>>(
      xn3, w_fc1, 8192, 2048, 512, hbuf, nullptr, b_fc1, nullptr);
  gemm_kernel<EPI_F32RES><<<dim3(4, 64), blk, 0, stream>>>(
      hbuf, w_fc2, 8192, 512, 2048, nullptr, out, b_fc2, x1);
  (void)in_sizes; (void)n_in; (void)out_size; (void)ws_size;
}

// Round 3
// 440.799 us; speedup vs baseline: 3.4047x; 3.4047x over previous
//
#include <hip/hip_runtime.h>

typedef unsigned short u16;
typedef short s16;
typedef u16 u16x8 __attribute__((ext_vector_type(8)));
typedef s16 s16x8 __attribute__((ext_vector_type(8)));
typedef float f32x4 __attribute__((ext_vector_type(4)));

__device__ __forceinline__ float b2f(u16 u) {
  union { unsigned int i; float f; } v;
  v.i = ((unsigned int)u) << 16;
  return v.f;
}
__device__ __forceinline__ u16 f2b(float f) {
  union { float f; unsigned int i; } v;
  v.f = f;
  unsigned int r = v.i + 0x7fffu + ((v.i >> 16) & 1u);
  return (u16)(r >> 16);
}

#define MFMA16(a, b, c) __builtin_amdgcn_mfma_f32_16x16x32_bf16(a, b, c, 0, 0, 0)

// ---------------- LayerNorm: fp32 in, bf16 out. One wave per 512-elem row ----------------
__global__ __launch_bounds__(256) void ln_kernel(const float* __restrict__ inv,
                                                 const float* __restrict__ w,
                                                 const float* __restrict__ bvec,
                                                 u16* __restrict__ out) {
  const int row = blockIdx.x * 4 + (threadIdx.x >> 6);
  const int lane = threadIdx.x & 63;
  const float* p = inv + (size_t)row * 512 + lane * 8;
  f32x4 v0 = *(const f32x4*)p;
  f32x4 v1 = *(const f32x4*)(p + 4);
  float x[8];
#pragma unroll
  for (int i = 0; i < 4; i++) { x[i] = v0[i]; x[4 + i] = v1[i]; }
  float s = 0.f;
#pragma unroll
  for (int i = 0; i < 8; i++) s += x[i];
#pragma unroll
  for (int m = 1; m < 64; m <<= 1) s += __shfl_xor(s, m, 64);
  const float mu = s * (1.0f / 512.0f);
  float vs = 0.f;
#pragma unroll
  for (int i = 0; i < 8; i++) { const float d = x[i] - mu; vs += d * d; }
#pragma unroll
  for (int m = 1; m < 64; m <<= 1) vs += __shfl_xor(vs, m, 64);
  const float r = rsqrtf(vs * (1.0f / 512.0f) + 1e-5f);
  const f32x4 w0 = *(const f32x4*)(w + lane * 8);
  const f32x4 w1 = *(const f32x4*)(w + lane * 8 + 4);
  const f32x4 b0 = *(const f32x4*)(bvec + lane * 8);
  const f32x4 b1 = *(const f32x4*)(bvec + lane * 8 + 4);
  u16x8 ov;
#pragma unroll
  for (int i = 0; i < 4; i++) {
    ov[i] = f2b((x[i] - mu) * r * w0[i] + b0[i]);
    ov[4 + i] = f2b((x[4 + i] - mu) * r * w1[i] + b1[i]);
  }
  *(u16x8*)(out + (size_t)row * 512 + lane * 8) = ov;
}

// ---------------- Weight transpose: W[K][N] fp32 -> Wt[N][K] bf16 ----------------
__global__ __launch_bounds__(256) void transp_kernel(const float* __restrict__ src,
                                                     u16* __restrict__ dst,
                                                     int K, int N) {
  __shared__ float T[64][65];
  const int n0 = blockIdx.x * 64, k0 = blockIdx.y * 64;
  const int c = threadIdx.x & 63, r0 = threadIdx.x >> 6;
#pragma unroll
  for (int i = 0; i < 16; i++) {
    const int r = i * 4 + r0;
    T[r][c] = src[(size_t)(k0 + r) * N + n0 + c];
  }
  __syncthreads();
#pragma unroll
  for (int i = 0; i < 16; i++) {
    const int r = i * 4 + r0;
    dst[(size_t)(n0 + r) * K + k0 + c] = f2b(T[c][r]);
  }
}

// ---------------- MFMA GEMM: C[M,N] = A[M,K](bf16) @ Bt[N,K]^T(bf16) ----------------
// 128x128 tile, BK=64, 4 waves each 64x64. LDS rows padded to 72 (2-way = free).
enum { EPI_NONE = 0, EPI_F32RES = 1, EPI_GELU = 2 };

template<int EPI>
__global__ __launch_bounds__(256) void mgemm(const u16* __restrict__ A,
                                             const u16* __restrict__ Bt,
                                             int M, int N, int K,
                                             u16* __restrict__ Cb,
                                             float* Cf,
                                             const float* __restrict__ bias,
                                             const float* resf) {
  __shared__ u16 As[128 * 72];
  __shared__ u16 Bs[128 * 72];
  const int tid = threadIdx.x;
  const int wv = tid >> 6, lane = tid & 63;
  const int quad = lane >> 4, l16 = lane & 15;
  const int wr = wv >> 1, wc = wv & 1;
  const int m0 = blockIdx.y * 128, n0 = blockIdx.x * 128;
  const int srow = tid >> 1, scol = (tid & 1) * 32;
  f32x4 acc[4][4];
#pragma unroll
  for (int i = 0; i < 4; i++)
#pragma unroll
    for (int j = 0; j < 4; j++) acc[i][j] = (f32x4){0.f, 0.f, 0.f, 0.f};
  const u16* Ap = A + (size_t)(m0 + srow) * K + scol;
  const u16* Bp = Bt + (size_t)(n0 + srow) * K + scol;
  for (int k0 = 0; k0 < K; k0 += 64) {
    s16x8 av[4], bv[4];
#pragma unroll
    for (int c = 0; c < 4; c++) {
      av[c] = *(const s16x8*)(Ap + k0 + c * 8);
      bv[c] = *(const s16x8*)(Bp + k0 + c * 8);
    }
    __syncthreads();
#pragma unroll
    for (int c = 0; c < 4; c++) {
      *(s16x8*)&As[srow * 72 + scol + c * 8] = av[c];
      *(s16x8*)&Bs[srow * 72 + scol + c * 8] = bv[c];
    }
    __syncthreads();
#pragma unroll
    for (int ks = 0; ks < 2; ks++) {
      s16x8 af[4], bf[4];
#pragma unroll
      for (int mt = 0; mt < 4; mt++)
        af[mt] = *(const s16x8*)&As[(wr * 64 + mt * 16 + l16) * 72 + ks * 32 + quad * 8];
#pragma unroll
      for (int nt = 0; nt < 4; nt++)
        bf[nt] = *(const s16x8*)&Bs[(wc * 64 + nt * 16 + l16) * 72 + ks * 32 + quad * 8];
#pragma unroll
      for (int mt = 0; mt < 4; mt++)
#pragma unroll
        for (int nt = 0; nt < 4; nt++)
          acc[mt][nt] = MFMA16(af[mt], bf[nt], acc[mt][nt]);
    }
  }
  // epilogue: lane holds C[m0+wr*64+mt*16+quad*4+r][n0+wc*64+nt*16+l16]
#pragma unroll
  for (int nt = 0; nt < 4; nt++) {
    const int n = n0 + wc * 64 + nt * 16 + l16;
    const float bn = (EPI != EPI_NONE) ? bias[n] : 0.f;
#pragma unroll
    for (int mt = 0; mt < 4; mt++) {
#pragma unroll
      for (int r = 0; r < 4; r++) {
        const int m = m0 + wr * 64 + mt * 16 + quad * 4 + r;
        float v = acc[mt][nt][r] + bn;
        if (EPI == EPI_GELU)
          v = 0.5f * v * (1.0f + erff(v * 0.70710678118654752f));
        if (EPI == EPI_F32RES) {
          const size_t idx = (size_t)m * N + n;
          Cf[idx] = v + resf[idx];
        } else {
          Cb[(size_t)m * N + n] = f2b(v);
        }
      }
    }
  }
}

// ---------------- KS = K+S (bf16) and V^T pre-pass, per (b,h) ----------------
// ksg layout: [bh][kk][64d]; vtg layout: [bh][d][2048kk]
__global__ __launch_bounds__(256) void ksvt_kernel(const u16* __restrict__ qkv,
                                                   const u16* __restrict__ sb,
                                                   u16* __restrict__ ksg,
                                                   u16* __restrict__ vtg) {
  __shared__ u16 T[64 * 72];
  const int bh = blockIdx.y;
  const int b = bh >> 3, h = bh & 7;
  const int kk0 = blockIdx.x * 64;
  const size_t rb = (size_t)b * 2048;
  const size_t base = (size_t)bh * 131072;
  const int row = threadIdx.x >> 2, cb = (threadIdx.x & 3) * 16;
  const u16* kp = qkv + (rb + kk0 + row) * 1536 + 512 + h * 64 + cb;
  const u16* sp = sb + (rb + kk0 + row) * 512 + h * 64 + cb;
  const u16x8 k0v = *(const u16x8*)kp;
  const u16x8 k1v = *(const u16x8*)(kp + 8);
  const u16x8 s0v = *(const u16x8*)sp;
  const u16x8 s1v = *(const u16x8*)(sp + 8);
  u16x8 o0, o1;
#pragma unroll
  for (int i = 0; i < 8; i++) {
    o0[i] = f2b(b2f(k0v[i]) + b2f(s0v[i]));
    o1[i] = f2b(b2f(k1v[i]) + b2f(s1v[i]));
  }
  *(u16x8*)(ksg + base + (size_t)(kk0 + row) * 64 + cb) = o0;
  *(u16x8*)(ksg + base + (size_t)(kk0 + row) * 64 + cb + 8) = o1;
  // V tile -> LDS row-major
  const u16x8 v0v = *(const u16x8*)(kp + 512);
  const u16x8 v1v = *(const u16x8*)(kp + 520);
  *(u16x8*)&T[row * 72 + cb] = v0v;
  *(u16x8*)&T[row * 72 + cb + 8] = v1v;
  __syncthreads();
  // write V^T: d = row, kk chunk = cb
  u16x8 a0, a1;
#pragma unroll
  for (int i = 0; i < 8; i++) {
    a0[i] = T[(cb + i) * 72 + row];
    a1[i] = T[(cb + 8 + i) * 72 + row];
  }
  *(u16x8*)(vtg + base + (size_t)row * 2048 + kk0 + cb) = a0;
  *(u16x8*)(vtg + base + (size_t)row * 2048 + kk0 + cb + 8) = a1;
}

// ---------------- MFMA flash attention: 64 q/block, wave = 16 q rows ----------------
__global__ __launch_bounds__(256) void attn_kernel(const u16* __restrict__ qkv,
                                                   const u16* __restrict__ ksg,
                                                   const u16* __restrict__ vtg,
                                                   u16* __restrict__ ob) {
  __shared__ u16 KSs[64 * 72];
  __shared__ u16 VTs[64 * 72];
  __shared__ u16 PS[4][16 * 72];
  const int tid = threadIdx.x;
  const int w = tid >> 6, lane = tid & 63;
  const int quad = lane >> 4, l16 = lane & 15;
  const int q0 = blockIdx.x * 64;
  const int bh = blockIdx.y;
  const int h = bh & 7;
  const size_t rb = (size_t)(bh >> 3) * 2048;
  const size_t base = (size_t)bh * 131072;

  // Q fragments (A-operand layout), scaled by 1/8 (exact in bf16)
  s16x8 aq[2];
  {
    const u16* qp = qkv + (rb + q0 + w * 16 + l16) * 1536 + h * 64 + quad * 8;
#pragma unroll
    for (int ks = 0; ks < 2; ks++) {
      const u16x8 qv = *(const u16x8*)(qp + ks * 32);
      s16x8 t;
#pragma unroll
      for (int i = 0; i < 8; i++) t[i] = (s16)f2b(b2f(qv[i]) * 0.125f);
      aq[ks] = t;
    }
  }
  float m_run[4], l_run[4];
  f32x4 oacc[4];
#pragma unroll
  for (int r = 0; r < 4; r++) { m_run[r] = -1e30f; l_run[r] = 0.f; }
#pragma unroll
  for (int nt = 0; nt < 4; nt++) oacc[nt] = (f32x4){0.f, 0.f, 0.f, 0.f};

  const int srow = tid >> 2, scb = (tid & 3) * 16;

  for (int kt = 0; kt < 32; kt++) {
    const int kk0 = kt * 64;
    {
      const u16* kp = ksg + base + (size_t)(kk0 + srow) * 64 + scb;
      const u16* vp = vtg + base + (size_t)srow * 2048 + kk0 + scb;
      const u16x8 a0 = *(const u16x8*)kp;
      const u16x8 a1 = *(const u16x8*)(kp + 8);
      const u16x8 b0 = *(const u16x8*)vp;
      const u16x8 b1 = *(const u16x8*)(vp + 8);
      *(u16x8*)&KSs[srow * 72 + scb] = a0;
      *(u16x8*)&KSs[srow * 72 + scb + 8] = a1;
      *(u16x8*)&VTs[srow * 72 + scb] = b0;
      *(u16x8*)&VTs[srow * 72 + scb + 8] = b1;
    }
    __syncthreads();
    // S = Q @ KS^T : D[q][kk], q=quad*4+r, kk=nt*16+l16
    f32x4 sacc[4];
#pragma unroll
    for (int nt = 0; nt < 4; nt++) sacc[nt] = (f32x4){0.f, 0.f, 0.f, 0.f};
#pragma unroll
    for (int ks = 0; ks < 2; ks++) {
#pragma unroll
      for (int nt = 0; nt < 4; nt++) {
        const s16x8 bfr = *(const s16x8*)&KSs[(nt * 16 + l16) * 72 + ks * 32 + quad * 8];
        sacc[nt] = MFMA16(aq[ks], bfr, sacc[nt]);
      }
    }
    // online softmax per q-row (r); row spans 16 lanes of the quad + 4 nt in-lane
    float alpha[4];
#pragma unroll
    for (int r = 0; r < 4; r++) {
      float rm = fmaxf(fmaxf(sacc[0][r], sacc[1][r]), fmaxf(sacc[2][r], sacc[3][r]));
      rm = fmaxf(rm, __shfl_xor(rm, 1, 64));
      rm = fmaxf(rm, __shfl_xor(rm, 2, 64));
      rm = fmaxf(rm, __shfl_xor(rm, 4, 64));
      rm = fmaxf(rm, __shfl_xor(rm, 8, 64));
      const float mo = m_run[r];
      const float mn = fmaxf(mo, rm);
      m_run[r] = mn;
      alpha[r] = __expf(mo - mn);
      float ps = 0.f;
#pragma unroll
      for (int nt = 0; nt < 4; nt++) {
        const float pv = __expf(sacc[nt][r] - mn);
        sacc[nt][r] = pv;
        ps += pv;
      }
      ps += __shfl_xor(ps, 1, 64);
      ps += __shfl_xor(ps, 2, 64);
      ps += __shfl_xor(ps, 4, 64);
      ps += __shfl_xor(ps, 8, 64);
      l_run[r] = l_run[r] * alpha[r] + ps;
    }
    // P: C-layout -> LDS [q][kk] (A-layout source)
#pragma unroll
    for (int nt = 0; nt < 4; nt++)
#pragma unroll
      for (int r = 0; r < 4; r++)
        PS[w][(quad * 4 + r) * 72 + nt * 16 + l16] = f2b(sacc[nt][r]);
#pragma unroll
    for (int nt = 0; nt < 4; nt++)
#pragma unroll
      for (int r = 0; r < 4; r++) oacc[nt][r] *= alpha[r];
    __syncthreads();
    // O += P @ V : A=P[q][kk], B-frag from V^T rows (d)
#pragma unroll
    for (int ks = 0; ks < 2; ks++) {
      const s16x8 pf = *(const s16x8*)&PS[w][l16 * 72 + ks * 32 + quad * 8];
#pragma unroll
      for (int nt = 0; nt < 4; nt++) {
        const s16x8 vf = *(const s16x8*)&VTs[(nt * 16 + l16) * 72 + ks * 32 + quad * 8];
        oacc[nt] = MFMA16(pf, vf, oacc[nt]);
      }
    }
    __syncthreads();
  }
#pragma unroll
  for (int r = 0; r < 4; r++) {
    const float rl = 1.0f / l_run[r];
    const size_t rowb = (rb + q0 + w * 16 + quad * 4 + r) * 512 + h * 64;
#pragma unroll
    for (int nt = 0; nt < 4; nt++)
      ob[rowb + nt * 16 + l16] = f2b(oacc[nt][r] * rl);
  }
}

// ---------------- elementwise o*gate (bf16) ----------------
__global__ __launch_bounds__(256) void ew_mul_kernel(const u16* __restrict__ a,
                                                     const u16* __restrict__ b,
                                                     u16* __restrict__ o) {
  const size_t idx = ((size_t)blockIdx.x * 256 + threadIdx.x) * 8;
  const u16x8 av = *(const u16x8*)(a + idx);
  const u16x8 bv = *(const u16x8*)(b + idx);
  u16x8 ov;
#pragma unroll
  for (int i = 0; i < 8; i++) ov[i] = f2b(b2f(av[i]) * b2f(bv[i]));
  *(u16x8*)(o + idx) = ov;
}

extern "C" void kernel_launch(void* const* d_in, const int* in_sizes, int n_in,
                              void* d_out, int out_size, void* d_ws, size_t ws_size,
                              hipStream_t stream) {
  const float* x      = (const float*)d_in[0];
  const float* e      = (const float*)d_in[1];
  const float* w_qkv  = (const float*)d_in[2];
  const float* w_s    = (const float*)d_in[3];
  const float* w_gate = (const float*)d_in[4];
  const float* w_proj = (const float*)d_in[5];
  const float* b_proj = (const float*)d_in[6];
  const float* ln1w   = (const float*)d_in[7];
  const float* ln1b   = (const float*)d_in[8];
  const float* ln2w   = (const float*)d_in[9];
  const float* ln2b   = (const float*)d_in[10];
  const float* ln3w   = (const float*)d_in[11];
  const float* ln3b   = (const float*)d_in[12];
  const float* w_fc1  = (const float*)d_in[13];
  const float* b_fc1  = (const float*)d_in[14];
  const float* w_fc2  = (const float*)d_in[15];
  const float* b_fc2  = (const float*)d_in[16];
  float* out = (float*)d_out;  // also serves as fp32 x1 (proj writes, ln3/fc2 read)
  char* ws = (char*)d_ws;

  // ws layout (79 MiB peak; round-2 proved >= 80 MiB available)
  u16* xn    = (u16*)(ws + 0);         // [ln1 -> gate], reused as xn3 [ln3 -> fc1]
  u16* en    = (u16*)(ws + 8388608);   // [ln2 -> sGEMM]; then KS_g [ksvt -> attn]; then og [ew -> proj]
  u16* qkv   = (u16*)(ws + 16777216);  // 24 MiB [qkvGEMM -> attn]; hbuf (32 MiB, 16..48M) [fc1 -> fc2]
  u16* sbuf  = (u16*)(ws + 41943040);  // [sGEMM -> ksvt]
  u16* gate  = (u16*)(ws + 50331648);  // [gateGEMM -> ew]
  u16* obuf  = (u16*)(ws + 58720256);  // [attn -> ew]
  u16* wqT   = (u16*)(ws + 67108864);  // 1536x512 bf16
  u16* wsT   = (u16*)(ws + 68681728);  // 512x512
  u16* wgT   = (u16*)(ws + 69206016);
  u16* wpT   = (u16*)(ws + 69730304);
  u16* wf1T  = (u16*)(ws + 70254592);  // 2048x512
  u16* wf2T  = (u16*)(ws + 72351744);  // 512x2048
  u16* vtg   = (u16*)(ws + 74448896);  // 8 MiB V^T [ksvt -> attn]
  u16* ksg   = en;
  u16* og    = en;
  u16* hbuf  = qkv;
  u16* xn3   = xn;

  dim3 blk(256);
  // weight transposes (fp32 -> bf16 W^T)
  transp_kernel<<<dim3(24, 8), blk, 0, stream>>>(w_qkv, wqT, 512, 1536);
  transp_kernel<<<dim3(8, 8), blk, 0, stream>>>(w_s, wsT, 512, 512);
  transp_kernel<<<dim3(8, 8), blk, 0, stream>>>(w_gate, wgT, 512, 512);
  transp_kernel<<<dim3(8, 8), blk, 0, stream>>>(w_proj, wpT, 512, 512);
  transp_kernel<<<dim3(32, 8), blk, 0, stream>>>(w_fc1, wf1T, 512, 2048);
  transp_kernel<<<dim3(8, 32), blk, 0, stream>>>(w_fc2, wf2T, 2048, 512);

  ln_kernel<<<2048, blk, 0, stream>>>(x, ln1w, ln1b, xn);
  ln_kernel<<<2048, blk, 0, stream>>>(e, ln2w, ln2b, en);
  mgemm<EPI_NONE><<<dim3(12, 64), blk, 0, stream>>>(
      xn, wqT, 8192, 1536, 512, qkv, nullptr, nullptr, nullptr);
  mgemm<EPI_NONE><<<dim3(4, 64), blk, 0, stream>>>(
      en, wsT, 8192, 512, 512, sbuf, nullptr, nullptr, nullptr);
  ksvt_kernel<<<dim3(32, 32), blk, 0, stream>>>(qkv, sbuf, ksg, vtg);
  mgemm<EPI_NONE><<<dim3(4, 64), blk, 0, stream>>>(
      xn, wgT, 8192, 512, 512, gate, nullptr, nullptr, nullptr);
  attn_kernel<<<dim3(32, 32), blk, 0, stream>>>(qkv, ksg, vtg, obuf);
  ew_mul_kernel<<<2048, blk, 0, stream>>>(obuf, gate, og);
  mgemm<EPI_F32RES><<<dim3(4, 64), blk, 0, stream>>>(
      og, wpT, 8192, 512, 512, nullptr, out, b_proj, x);
  ln_kernel<<<2048, blk, 0, stream>>>(out, ln3w, ln3b, xn3);
  mgemm<EPI_GELU><<<dim3(16, 64), blk, 0, stream>>>(
      xn3, wf1T, 8192, 2048, 512, hbuf, nullptr, b_fc1, nullptr);
  mgemm<EPI_F32RES><<<dim3(4, 64), blk, 0, stream>>>(
      hbuf, wf2T, 8192, 512, 2048, nullptr, out, b_fc2, out);
  (void)in_sizes; (void)n_in; (void)out_size; (void)ws_size;
}

// Round 4
// 405.249 us; speedup vs baseline: 3.7033x; 1.0877x over previous
//
#include <hip/hip_runtime.h>

typedef unsigned short u16;
typedef short s16;
typedef u16 u16x4 __attribute__((ext_vector_type(4)));
typedef u16 u16x8 __attribute__((ext_vector_type(8)));
typedef s16 s16x8 __attribute__((ext_vector_type(8)));
typedef float f32x4 __attribute__((ext_vector_type(4)));

__device__ __forceinline__ float b2f(u16 u) {
  union { unsigned int i; float f; } v;
  v.i = ((unsigned int)u) << 16;
  return v.f;
}
__device__ __forceinline__ u16 f2b(float f) {
  union { float f; unsigned int i; } v;
  v.f = f;
  unsigned int r = v.i + 0x7fffu + ((v.i >> 16) & 1u);
  return (u16)(r >> 16);
}

#define MFMA16(a, b, c) __builtin_amdgcn_mfma_f32_16x16x32_bf16(a, b, c, 0, 0, 0)

// async global->LDS, 16B per lane; LDS dest = wave-uniform base + lane*16
__device__ __forceinline__ void gld16(const u16* g, u16* l) {
  __builtin_amdgcn_global_load_lds(
      (const __attribute__((address_space(1))) void*)g,
      (__attribute__((address_space(3))) void*)l, 16, 0, 0);
}

// ---------------- LayerNorm: fp32 in, bf16 out. One wave per 512-elem row ----------------
__global__ __launch_bounds__(256) void ln_kernel(const float* __restrict__ inv,
                                                 const float* __restrict__ w,
                                                 const float* __restrict__ bvec,
                                                 u16* __restrict__ out) {
  const int row = blockIdx.x * 4 + (threadIdx.x >> 6);
  const int lane = threadIdx.x & 63;
  const float* p = inv + (size_t)row * 512 + lane * 8;
  f32x4 v0 = *(const f32x4*)p;
  f32x4 v1 = *(const f32x4*)(p + 4);
  float x[8];
#pragma unroll
  for (int i = 0; i < 4; i++) { x[i] = v0[i]; x[4 + i] = v1[i]; }
  float s = 0.f;
#pragma unroll
  for (int i = 0; i < 8; i++) s += x[i];
#pragma unroll
  for (int m = 1; m < 64; m <<= 1) s += __shfl_xor(s, m, 64);
  const float mu = s * (1.0f / 512.0f);
  float vs = 0.f;
#pragma unroll
  for (int i = 0; i < 8; i++) { const float d = x[i] - mu; vs += d * d; }
#pragma unroll
  for (int m = 1; m < 64; m <<= 1) vs += __shfl_xor(vs, m, 64);
  const float r = rsqrtf(vs * (1.0f / 512.0f) + 1e-5f);
  const f32x4 w0 = *(const f32x4*)(w + lane * 8);
  const f32x4 w1 = *(const f32x4*)(w + lane * 8 + 4);
  const f32x4 b0 = *(const f32x4*)(bvec + lane * 8);
  const f32x4 b1 = *(const f32x4*)(bvec + lane * 8 + 4);
  u16x8 ov;
#pragma unroll
  for (int i = 0; i < 4; i++) {
    ov[i] = f2b((x[i] - mu) * r * w0[i] + b0[i]);
    ov[4 + i] = f2b((x[4 + i] - mu) * r * w1[i] + b1[i]);
  }
  *(u16x8*)(out + (size_t)row * 512 + lane * 8) = ov;
}

// ---------------- Weight transpose: W[K][N] fp32 -> Wt[N][K] bf16 ----------------
__global__ __launch_bounds__(256) void transp_kernel(const float* __restrict__ src,
                                                     u16* __restrict__ dst,
                                                     int K, int N) {
  __shared__ float T[64][65];
  const int n0 = blockIdx.x * 64, k0 = blockIdx.y * 64;
  const int c = threadIdx.x & 63, r0 = threadIdx.x >> 6;
#pragma unroll
  for (int i = 0; i < 16; i++) {
    const int r = i * 4 + r0;
    T[r][c] = src[(size_t)(k0 + r) * N + n0 + c];
  }
  __syncthreads();
#pragma unroll
  for (int i = 0; i < 16; i++) {
    const int r = i * 4 + r0;
    dst[(size_t)(n0 + r) * K + k0 + c] = f2b(T[c][r]);
  }
}

// ---------------- MFMA GEMM (m97-style staging): C = A[M,K] @ Bt[N,K]^T ----------------
// BM=128: 4 waves in 2x2, each 64x64. BM=64: 4 waves side-by-side, each 64x32.
// BK=64, LDS unpadded (global_load_lds), 128-col N tile.
enum { EPI_NONE = 0, EPI_F32RES = 1, EPI_GELU = 2 };

template<int EPI, int BM>
__global__ __launch_bounds__(256) void mgemm(const u16* __restrict__ A,
                                             const u16* __restrict__ Bt,
                                             int M, int N, int K,
                                             u16* __restrict__ Cb, float* Cf,
                                             const float* __restrict__ bias,
                                             const float* resf) {
  constexpr int NT = (BM == 128) ? 4 : 2;
  constexpr int ACH = BM / 32;  // A 1-KiB chunks per wave
  __shared__ u16 As[BM * 64];
  __shared__ u16 Bs[128 * 64];
  const int tid = threadIdx.x;
  const int wv = tid >> 6, lane = tid & 63;
  const int quad = lane >> 4, l16 = lane & 15;
  const int wrow = (BM == 128) ? (wv >> 1) * 64 : 0;
  const int wcol = (BM == 128) ? (wv & 1) * 64 : wv * 32;
  const int m0 = blockIdx.y * BM, n0 = blockIdx.x * 128;
  const int lrow = lane >> 3, lcol = (lane & 7) * 8;
  f32x4 acc[4][NT];
#pragma unroll
  for (int i = 0; i < 4; i++)
#pragma unroll
    for (int j = 0; j < NT; j++) acc[i][j] = (f32x4){0.f, 0.f, 0.f, 0.f};
  for (int k0 = 0; k0 < K; k0 += 64) {
    __syncthreads();
#pragma unroll
    for (int i = 0; i < ACH; i++) {
      const int ch = wv * ACH + i;
      gld16(A + (size_t)(m0 + ch * 8 + lrow) * K + k0 + lcol, &As[ch * 512]);
    }
#pragma unroll
    for (int i = 0; i < 4; i++) {
      const int ch = wv * 4 + i;
      gld16(Bt + (size_t)(n0 + ch * 8 + lrow) * K + k0 + lcol, &Bs[ch * 512]);
    }
    __syncthreads();
#pragma unroll
    for (int ks = 0; ks < 2; ks++) {
      s16x8 af[4], bf[NT];
#pragma unroll
      for (int mt = 0; mt < 4; mt++)
        af[mt] = *(const s16x8*)&As[(wrow + mt * 16 + l16) * 64 + ks * 32 + quad * 8];
#pragma unroll
      for (int nt = 0; nt < NT; nt++)
        bf[nt] = *(const s16x8*)&Bs[(wcol + nt * 16 + l16) * 64 + ks * 32 + quad * 8];
#pragma unroll
      for (int mt = 0; mt < 4; mt++)
#pragma unroll
        for (int nt = 0; nt < NT; nt++)
          acc[mt][nt] = MFMA16(af[mt], bf[nt], acc[mt][nt]);
    }
  }
#pragma unroll
  for (int nt = 0; nt < NT; nt++) {
    const int n = n0 + wcol + nt * 16 + l16;
    const float bn = (EPI != EPI_NONE) ? bias[n] : 0.f;
#pragma unroll
    for (int mt = 0; mt < 4; mt++) {
#pragma unroll
      for (int r = 0; r < 4; r++) {
        const int m = m0 + wrow + mt * 16 + quad * 4 + r;
        float v = acc[mt][nt][r] + bn;
        if (EPI == EPI_GELU)
          v = 0.5f * v * (1.0f + erff(v * 0.70710678118654752f));
        if (EPI == EPI_F32RES) {
          const size_t idx = (size_t)m * N + n;
          Cf[idx] = v + resf[idx];
        } else {
          Cb[(size_t)m * N + n] = f2b(v);
        }
      }
    }
  }
}

// ---------------- KS = K+S (bf16) and V^T pre-pass, per (b,h) ----------------
// ksg layout: [bh][kk][64d]; vtg layout: [bh][d][2048kk]
__global__ __launch_bounds__(256) void ksvt_kernel(const u16* __restrict__ qkv,
                                                   const u16* __restrict__ sb,
                                                   u16* __restrict__ ksg,
                                                   u16* __restrict__ vtg) {
  __shared__ u16 T[64 * 72];
  const int bh = blockIdx.y;
  const int b = bh >> 3, h = bh & 7;
  const int kk0 = blockIdx.x * 64;
  const size_t rb = (size_t)b * 2048;
  const size_t base = (size_t)bh * 131072;
  const int row = threadIdx.x >> 2, cb = (threadIdx.x & 3) * 16;
  const u16* kp = qkv + (rb + kk0 + row) * 1536 + 512 + h * 64 + cb;
  const u16* sp = sb + (rb + kk0 + row) * 512 + h * 64 + cb;
  const u16x8 k0v = *(const u16x8*)kp;
  const u16x8 k1v = *(const u16x8*)(kp + 8);
  const u16x8 s0v = *(const u16x8*)sp;
  const u16x8 s1v = *(const u16x8*)(sp + 8);
  u16x8 o0, o1;
#pragma unroll
  for (int i = 0; i < 8; i++) {
    o0[i] = f2b(b2f(k0v[i]) + b2f(s0v[i]));
    o1[i] = f2b(b2f(k1v[i]) + b2f(s1v[i]));
  }
  *(u16x8*)(ksg + base + (size_t)(kk0 + row) * 64 + cb) = o0;
  *(u16x8*)(ksg + base + (size_t)(kk0 + row) * 64 + cb + 8) = o1;
  const u16x8 v0v = *(const u16x8*)(kp + 512);
  const u16x8 v1v = *(const u16x8*)(kp + 520);
  *(u16x8*)&T[row * 72 + cb] = v0v;
  *(u16x8*)&T[row * 72 + cb + 8] = v1v;
  __syncthreads();
  u16x8 a0, a1;
#pragma unroll
  for (int i = 0; i < 8; i++) {
    a0[i] = T[(cb + i) * 72 + row];
    a1[i] = T[(cb + 8 + i) * 72 + row];
  }
  *(u16x8*)(vtg + base + (size_t)row * 2048 + kk0 + cb) = a0;
  *(u16x8*)(vtg + base + (size_t)row * 2048 + kk0 + cb + 8) = a1;
}

// ---------------- MFMA flash attention, S^T softmax. 64 q/block, wave = 16 q ----------------
__global__ __launch_bounds__(256) void attn_kernel(const u16* __restrict__ qkv,
                                                   const u16* __restrict__ ksg,
                                                   const u16* __restrict__ vtg,
                                                   u16* __restrict__ ob) {
  __shared__ u16 KSs[64 * 64];  // [k][d], unpadded (gld staging)
  __shared__ u16 VTs[64 * 64];  // [d][k], unpadded
  __shared__ u16 PS[4][16 * 72];
  const int tid = threadIdx.x;
  const int w = tid >> 6, lane = tid & 63;
  const int quad = lane >> 4, l16 = lane & 15;
  const int q0 = blockIdx.x * 64;
  const int bh = blockIdx.y;
  const int h = bh & 7;
  const size_t rb = (size_t)(bh >> 3) * 2048;
  const size_t base = (size_t)bh * 131072;
  const int lrow = lane >> 3, lcol = (lane & 7) * 8;

  // Q fragments (A/B-operand layout: lane=q row, quad*8 d-offset), scaled 1/8 (exact)
  s16x8 aq[2];
  {
    const u16* qp = qkv + (rb + q0 + w * 16 + l16) * 1536 + h * 64 + quad * 8;
#pragma unroll
    for (int ks = 0; ks < 2; ks++) {
      const u16x8 qv = *(const u16x8*)(qp + ks * 32);
      s16x8 t;
#pragma unroll
      for (int i = 0; i < 8; i++) t[i] = (s16)f2b(b2f(qv[i]) * 0.125f);
      aq[ks] = t;
    }
  }
  // running softmax state for q = l16 (replicated across quads)
  float m_run = -1e30f, l_run = 0.f;
  f32x4 oacc[4];
#pragma unroll
  for (int nt = 0; nt < 4; nt++) oacc[nt] = (f32x4){0.f, 0.f, 0.f, 0.f};

  for (int kt = 0; kt < 32; kt++) {
    const int kk0 = kt * 64;
    __syncthreads();
#pragma unroll
    for (int i = 0; i < 2; i++) {
      const int ch = w * 2 + i;
      gld16(ksg + base + (size_t)kk0 * 64 + ch * 512 + lane * 8, &KSs[ch * 512]);
      gld16(vtg + base + (size_t)(ch * 8 + lrow) * 2048 + kk0 + lcol, &VTs[ch * 512]);
    }
    __syncthreads();
    // S^T[k][q] = KS @ Q^T : A-frag = KS rows, B-frag = aq regs.
    // D: col=l16=q, row=quad*4+r=k (within mt*16 block)
    f32x4 sacc[4];
#pragma unroll
    for (int mt = 0; mt < 4; mt++) sacc[mt] = (f32x4){0.f, 0.f, 0.f, 0.f};
#pragma unroll
    for (int ks = 0; ks < 2; ks++) {
#pragma unroll
      for (int mt = 0; mt < 4; mt++) {
        const s16x8 kf = *(const s16x8*)&KSs[(mt * 16 + l16) * 64 + ks * 32 + quad * 8];
        sacc[mt] = MFMA16(kf, aq[ks], sacc[mt]);
      }
    }
    // online softmax for q=l16: lane holds 16 k-scores; quads hold disjoint k
    float lm = -1e30f;
#pragma unroll
    for (int mt = 0; mt < 4; mt++)
#pragma unroll
      for (int r = 0; r < 4; r++) lm = fmaxf(lm, sacc[mt][r]);
    lm = fmaxf(lm, __shfl_xor(lm, 16, 64));
    lm = fmaxf(lm, __shfl_xor(lm, 32, 64));
    const float mn = fmaxf(m_run, lm);
    const float alpha = __expf(m_run - mn);
    m_run = mn;
    float ls = 0.f;
#pragma unroll
    for (int mt = 0; mt < 4; mt++) {
#pragma unroll
      for (int r = 0; r < 4; r++) {
        const float pv = __expf(sacc[mt][r] - mn);
        sacc[mt][r] = pv;
        ls += pv;
      }
    }
    ls += __shfl_xor(ls, 16, 64);
    ls += __shfl_xor(ls, 32, 64);
    l_run = l_run * alpha + ls;
    // P store: lane owns q=l16, k = mt*16 + quad*4 + (0..3) -> contiguous b64
#pragma unroll
    for (int mt = 0; mt < 4; mt++) {
      u16x4 pk;
#pragma unroll
      for (int r = 0; r < 4; r++) pk[r] = f2b(sacc[mt][r]);
      *(u16x4*)&PS[w][l16 * 72 + mt * 16 + quad * 4] = pk;
    }
    // rescale oacc rows (q = quad*4+r): fetch alpha from lane quad*4+r
#pragma unroll
    for (int r = 0; r < 4; r++) {
      const float af = __shfl(alpha, quad * 4 + r, 64);
#pragma unroll
      for (int nt = 0; nt < 4; nt++) oacc[nt][r] *= af;
    }
    // O += P @ V : A = P[q][k] from PS, B-frag = V^T rows
#pragma unroll
    for (int ks = 0; ks < 2; ks++) {
      const s16x8 pf = *(const s16x8*)&PS[w][l16 * 72 + ks * 32 + quad * 8];
#pragma unroll
      for (int nt = 0; nt < 4; nt++) {
        const s16x8 vf = *(const s16x8*)&VTs[(nt * 16 + l16) * 64 + ks * 32 + quad * 8];
        oacc[nt] = MFMA16(pf, vf, oacc[nt]);
      }
    }
  }
  const float lq = __shfl(l_run, quad * 4 + (lane & 3), 64);  // placeholder avoid unused
  (void)lq;
#pragma unroll
  for (int r = 0; r < 4; r++) {
    const float linv = 1.0f / __shfl(l_run, quad * 4 + r, 64);
    const size_t rowb = (rb + q0 + w * 16 + quad * 4 + r) * 512 + h * 64;
#pragma unroll
    for (int nt = 0; nt < 4; nt++)
      ob[rowb + nt * 16 + l16] = f2b(oacc[nt][r] * linv);
  }
}

// ---------------- elementwise o*gate (bf16) ----------------
__global__ __launch_bounds__(256) void ew_mul_kernel(const u16* __restrict__ a,
                                                     const u16* __restrict__ b,
                                                     u16* __restrict__ o) {
  const size_t idx = ((size_t)blockIdx.x * 256 + threadIdx.x) * 8;
  const u16x8 av = *(const u16x8*)(a + idx);
  const u16x8 bv = *(const u16x8*)(b + idx);
  u16x8 ov;
#pragma unroll
  for (int i = 0; i < 8; i++) ov[i] = f2b(b2f(av[i]) * b2f(bv[i]));
  *(u16x8*)(o + idx) = ov;
}

extern "C" void kernel_launch(void* const* d_in, const int* in_sizes, int n_in,
                              void* d_out, int out_size, void* d_ws, size_t ws_size,
                              hipStream_t stream) {
  const float* x      = (const float*)d_in[0];
  const float* e      = (const float*)d_in[1];
  const float* w_qkv  = (const float*)d_in[2];
  const float* w_s    = (const float*)d_in[3];
  const float* w_gate = (const float*)d_in[4];
  const float* w_proj = (const float*)d_in[5];
  const float* b_proj = (const float*)d_in[6];
  const float* ln1w   = (const float*)d_in[7];
  const float* ln1b   = (const float*)d_in[8];
  const float* ln2w   = (const float*)d_in[9];
  const float* ln2b   = (const float*)d_in[10];
  const float* ln3w   = (const float*)d_in[11];
  const float* ln3b   = (const float*)d_in[12];
  const float* w_fc1  = (const float*)d_in[13];
  const float* b_fc1  = (const float*)d_in[14];
  const float* w_fc2  = (const float*)d_in[15];
  const float* b_fc2  = (const float*)d_in[16];
  float* out = (float*)d_out;  // also fp32 x1 (proj writes, ln3/fc2 read)
  char* ws = (char*)d_ws;

  u16* xn    = (u16*)(ws + 0);         // ln1 -> qkv/gate; reused as xn3
  u16* en    = (u16*)(ws + 8388608);   // ln2 -> sGEMM; then ksg; then og
  u16* qkv   = (u16*)(ws + 16777216);  // 24 MiB; hbuf (32 MiB) for fc1->fc2
  u16* sbuf  = (u16*)(ws + 41943040);
  u16* gate  = (u16*)(ws + 50331648);
  u16* obuf  = (u16*)(ws + 58720256);
  u16* wqT   = (u16*)(ws + 67108864);  // 1536x512 bf16
  u16* wsT   = (u16*)(ws + 68681728);
  u16* wgT   = (u16*)(ws + 69206016);
  u16* wpT   = (u16*)(ws + 69730304);
  u16* wf1T  = (u16*)(ws + 70254592);  // 2048x512
  u16* wf2T  = (u16*)(ws + 72351744);  // 512x2048
  u16* vtg   = (u16*)(ws + 74448896);  // 8 MiB V^T
  u16* ksg   = en;
  u16* og    = en;
  u16* hbuf  = qkv;
  u16* xn3   = xn;

  dim3 blk(256);
  transp_kernel<<<dim3(24, 8), blk, 0, stream>>>(w_qkv, wqT, 512, 1536);
  transp_kernel<<<dim3(8, 8), blk, 0, stream>>>(w_s, wsT, 512, 512);
  transp_kernel<<<dim3(8, 8), blk, 0, stream>>>(w_gate, wgT, 512, 512);
  transp_kernel<<<dim3(8, 8), blk, 0, stream>>>(w_proj, wpT, 512, 512);
  transp_kernel<<<dim3(32, 8), blk, 0, stream>>>(w_fc1, wf1T, 512, 2048);
  transp_kernel<<<dim3(8, 32), blk, 0, stream>>>(w_fc2, wf2T, 2048, 512);

  ln_kernel<<<2048, blk, 0, stream>>>(x, ln1w, ln1b, xn);
  ln_kernel<<<2048, blk, 0, stream>>>(e, ln2w, ln2b, en);
  mgemm<EPI_NONE, 128><<<dim3(12, 64), blk, 0, stream>>>(
      xn, wqT, 8192, 1536, 512, qkv, nullptr, nullptr, nullptr);
  mgemm<EPI_NONE, 64><<<dim3(4, 128), blk, 0, stream>>>(
      en, wsT, 8192, 512, 512, sbuf, nullptr, nullptr, nullptr);
  ksvt_kernel<<<dim3(32, 32), blk, 0, stream>>>(qkv, sbuf, ksg, vtg);
  mgemm<EPI_NONE, 64><<<dim3(4, 128), blk, 0, stream>>>(
      xn, wgT, 8192, 512, 512, gate, nullptr, nullptr, nullptr);
  attn_kernel<<<dim3(32, 32), blk, 0, stream>>>(qkv, ksg, vtg, obuf);
  ew_mul_kernel<<<2048, blk, 0, stream>>>(obuf, gate, og);
  mgemm<EPI_F32RES, 64><<<dim3(4, 128), blk, 0, stream>>>(
      og, wpT, 8192, 512, 512, nullptr, out, b_proj, x);
  ln_kernel<<<2048, blk, 0, stream>>>(out, ln3w, ln3b, xn3);
  mgemm<EPI_GELU, 128><<<dim3(16, 64), blk, 0, stream>>>(
      xn3, wf1T, 8192, 2048, 512, hbuf, nullptr, b_fc1, nullptr);
  mgemm<EPI_F32RES, 64><<<dim3(4, 128), blk, 0, stream>>>(
      hbuf, wf2T, 8192, 512, 2048, nullptr, out, b_fc2, out);
  (void)in_sizes; (void)n_in; (void)out_size; (void)ws_size;
}

// Round 5
// 351.092 us; speedup vs baseline: 4.2746x; 1.1543x over previous
//
#include <hip/hip_runtime.h>

typedef unsigned short u16;
typedef short s16;
typedef u16 u16x4 __attribute__((ext_vector_type(4)));
typedef u16 u16x8 __attribute__((ext_vector_type(8)));
typedef s16 s16x8 __attribute__((ext_vector_type(8)));
typedef float f32x4 __attribute__((ext_vector_type(4)));

__device__ __forceinline__ float b2f(u16 u) {
  union { unsigned int i; float f; } v;
  v.i = ((unsigned int)u) << 16;
  return v.f;
}
__device__ __forceinline__ u16 f2b(float f) {
  union { float f; unsigned int i; } v;
  v.f = f;
  unsigned int r = v.i + 0x7fffu + ((v.i >> 16) & 1u);
  return (u16)(r >> 16);
}

#define MFMA16(a, b, c) __builtin_amdgcn_mfma_f32_16x16x32_bf16(a, b, c, 0, 0, 0)

// async global->LDS: 16B/lane, LDS dest = wave-uniform base + lane*16
__device__ __forceinline__ void gld16(const u16* g, u16* l) {
  __builtin_amdgcn_global_load_lds(
      (const __attribute__((address_space(1))) void*)g,
      (__attribute__((address_space(3))) void*)l, 16, 0, 0);
}

// ---------------- fused LN1+LN2: fp32 in, bf16 out ----------------
__global__ __launch_bounds__(256) void ln12_kernel(
    const float* __restrict__ x, const float* __restrict__ e,
    const float* __restrict__ w1, const float* __restrict__ b1,
    const float* __restrict__ w2, const float* __restrict__ b2,
    u16* __restrict__ xn, u16* __restrict__ en) {
  int bid = blockIdx.x;
  const float *inv, *w, *bb;
  u16* out;
  if (bid < 2048) { inv = x; w = w1; bb = b1; out = xn; }
  else { bid -= 2048; inv = e; w = w2; bb = b2; out = en; }
  const int row = bid * 4 + (threadIdx.x >> 6);
  const int lane = threadIdx.x & 63;
  const float* p = inv + (size_t)row * 512 + lane * 8;
  f32x4 v0 = *(const f32x4*)p;
  f32x4 v1 = *(const f32x4*)(p + 4);
  float xv[8];
#pragma unroll
  for (int i = 0; i < 4; i++) { xv[i] = v0[i]; xv[4 + i] = v1[i]; }
  float s = 0.f;
#pragma unroll
  for (int i = 0; i < 8; i++) s += xv[i];
#pragma unroll
  for (int m = 1; m < 64; m <<= 1) s += __shfl_xor(s, m, 64);
  const float mu = s * (1.0f / 512.0f);
  float vs = 0.f;
#pragma unroll
  for (int i = 0; i < 8; i++) { const float d = xv[i] - mu; vs += d * d; }
#pragma unroll
  for (int m = 1; m < 64; m <<= 1) vs += __shfl_xor(vs, m, 64);
  const float r = rsqrtf(vs * (1.0f / 512.0f) + 1e-5f);
  const f32x4 w0 = *(const f32x4*)(w + lane * 8);
  const f32x4 w1v = *(const f32x4*)(w + lane * 8 + 4);
  const f32x4 bb0 = *(const f32x4*)(bb + lane * 8);
  const f32x4 bb1 = *(const f32x4*)(bb + lane * 8 + 4);
  u16x8 ov;
#pragma unroll
  for (int i = 0; i < 4; i++) {
    ov[i] = f2b((xv[i] - mu) * r * w0[i] + bb0[i]);
    ov[4 + i] = f2b((xv[4 + i] - mu) * r * w1v[i] + bb1[i]);
  }
  *(u16x8*)(out + (size_t)row * 512 + lane * 8) = ov;
}

// ---------------- LN3 (single input) ----------------
__global__ __launch_bounds__(256) void ln_kernel(const float* __restrict__ inv,
                                                 const float* __restrict__ w,
                                                 const float* __restrict__ bvec,
                                                 u16* __restrict__ out) {
  const int row = blockIdx.x * 4 + (threadIdx.x >> 6);
  const int lane = threadIdx.x & 63;
  const float* p = inv + (size_t)row * 512 + lane * 8;
  f32x4 v0 = *(const f32x4*)p;
  f32x4 v1 = *(const f32x4*)(p + 4);
  float x[8];
#pragma unroll
  for (int i = 0; i < 4; i++) { x[i] = v0[i]; x[4 + i] = v1[i]; }
  float s = 0.f;
#pragma unroll
  for (int i = 0; i < 8; i++) s += x[i];
#pragma unroll
  for (int m = 1; m < 64; m <<= 1) s += __shfl_xor(s, m, 64);
  const float mu = s * (1.0f / 512.0f);
  float vs = 0.f;
#pragma unroll
  for (int i = 0; i < 8; i++) { const float d = x[i] - mu; vs += d * d; }
#pragma unroll
  for (int m = 1; m < 64; m <<= 1) vs += __shfl_xor(vs, m, 64);
  const float r = rsqrtf(vs * (1.0f / 512.0f) + 1e-5f);
  const f32x4 w0 = *(const f32x4*)(w + lane * 8);
  const f32x4 w1 = *(const f32x4*)(w + lane * 8 + 4);
  const f32x4 b0 = *(const f32x4*)(bvec + lane * 8);
  const f32x4 b1 = *(const f32x4*)(bvec + lane * 8 + 4);
  u16x8 ov;
#pragma unroll
  for (int i = 0; i < 4; i++) {
    ov[i] = f2b((x[i] - mu) * r * w0[i] + b0[i]);
    ov[4 + i] = f2b((x[4 + i] - mu) * r * w1[i] + b1[i]);
  }
  *(u16x8*)(out + (size_t)row * 512 + lane * 8) = ov;
}

// ---------------- fused weight prep: 6 transposes (fp32 W[K][N] -> bf16 Wt[N][K]) ----------------
__global__ __launch_bounds__(256) void wprep_kernel(
    const float* __restrict__ wq, const float* __restrict__ wsc,
    const float* __restrict__ wg, const float* __restrict__ wp,
    const float* __restrict__ w1, const float* __restrict__ w2,
    u16* __restrict__ wqgT, u16* __restrict__ wsT, u16* __restrict__ wpT,
    u16* __restrict__ wf1T, u16* __restrict__ wf2T) {
  __shared__ float T[64][65];
  int bid = blockIdx.x;
  const float* src; u16* dst; int K, N, ntiles;
  if (bid < 192)      { src = wq;  dst = wqgT;              K = 512;  N = 1536; ntiles = 24; }
  else if (bid < 256) { src = wg;  dst = wqgT + 1536 * 512; K = 512;  N = 512;  ntiles = 8; bid -= 192; }
  else if (bid < 320) { src = wsc; dst = wsT;               K = 512;  N = 512;  ntiles = 8; bid -= 256; }
  else if (bid < 384) { src = wp;  dst = wpT;               K = 512;  N = 512;  ntiles = 8; bid -= 320; }
  else if (bid < 640) { src = w1;  dst = wf1T;              K = 512;  N = 2048; ntiles = 32; bid -= 384; }
  else                { src = w2;  dst = wf2T;              K = 2048; N = 512;  ntiles = 8; bid -= 640; }
  const int n0 = (bid % ntiles) * 64, k0 = (bid / ntiles) * 64;
  const int c = threadIdx.x & 63, r0 = threadIdx.x >> 6;
#pragma unroll
  for (int i = 0; i < 16; i++) {
    const int r = i * 4 + r0;
    T[r][c] = src[(size_t)(k0 + r) * N + n0 + c];
  }
  __syncthreads();
#pragma unroll
  for (int i = 0; i < 16; i++) {
    const int r = i * 4 + r0;
    dst[(size_t)(n0 + r) * K + k0 + c] = f2b(T[c][r]);
  }
}

// ---------------- MFMA GEMM, XOR-swizzled LDS: C = A[M,K] @ Bt[N,K]^T ----------------
// BM=128: 4 waves 2x2 (64x64 each). BM=64: 4 waves side-by-side (64x32 each).
// BK=64. Physical chunk = logical chunk ^ (row&7): staging picks swizzled global
// chunk; frag reads XOR the chunk index -> 2-way bank aliasing only (free, m136).
enum { EPI_NONE = 0, EPI_F32RES = 1, EPI_GELU = 2 };

template<int EPI, int BM>
__global__ __launch_bounds__(256) void mgemm(const u16* __restrict__ A,
                                             const u16* __restrict__ Bt,
                                             int M, int N, int K,
                                             u16* __restrict__ Cb, float* Cf,
                                             const float* __restrict__ bias,
                                             const float* resf) {
  constexpr int NT = (BM == 128) ? 4 : 2;
  constexpr int ACH = BM / 32;
  __shared__ u16 As[BM * 64];
  __shared__ u16 Bs[128 * 64];
  const int tid = threadIdx.x;
  const int wv = tid >> 6, lane = tid & 63;
  const int quad = lane >> 4, l16 = lane & 15;
  const int sw = l16 & 7;
  const int wrow = (BM == 128) ? (wv >> 1) * 64 : 0;
  const int wcol = (BM == 128) ? (wv & 1) * 64 : wv * 32;
  const int m0 = blockIdx.y * BM, n0 = blockIdx.x * 128;
  const int lrow = lane >> 3;
  const int lcs = ((lane & 7) ^ lrow) * 8;  // swizzled source chunk
  f32x4 acc[4][NT];
#pragma unroll
  for (int i = 0; i < 4; i++)
#pragma unroll
    for (int j = 0; j < NT; j++) acc[i][j] = (f32x4){0.f, 0.f, 0.f, 0.f};
  for (int k0 = 0; k0 < K; k0 += 64) {
    __syncthreads();
#pragma unroll
    for (int i = 0; i < ACH; i++) {
      const int ch = wv * ACH + i;
      gld16(A + (size_t)(m0 + ch * 8 + lrow) * K + k0 + lcs, &As[ch * 512]);
    }
#pragma unroll
    for (int i = 0; i < 4; i++) {
      const int ch = wv * 4 + i;
      gld16(Bt + (size_t)(n0 + ch * 8 + lrow) * K + k0 + lcs, &Bs[ch * 512]);
    }
    __syncthreads();
#pragma unroll
    for (int ks = 0; ks < 2; ks++) {
      s16x8 af[4], bf[NT];
#pragma unroll
      for (int mt = 0; mt < 4; mt++)
        af[mt] = *(const s16x8*)&As[(wrow + mt * 16 + l16) * 64 +
                                    (((ks * 4 + quad) ^ sw) * 8)];
#pragma unroll
      for (int nt = 0; nt < NT; nt++)
        bf[nt] = *(const s16x8*)&Bs[(wcol + nt * 16 + l16) * 64 +
                                    (((ks * 4 + quad) ^ sw) * 8)];
#pragma unroll
      for (int mt = 0; mt < 4; mt++)
#pragma unroll
        for (int nt = 0; nt < NT; nt++)
          acc[mt][nt] = MFMA16(af[mt], bf[nt], acc[mt][nt]);
    }
  }
#pragma unroll
  for (int nt = 0; nt < NT; nt++) {
    const int n = n0 + wcol + nt * 16 + l16;
    const float bn = (EPI != EPI_NONE) ? bias[n] : 0.f;
#pragma unroll
    for (int mt = 0; mt < 4; mt++) {
#pragma unroll
      for (int r = 0; r < 4; r++) {
        const int m = m0 + wrow + mt * 16 + quad * 4 + r;
        float v = acc[mt][nt][r] + bn;
        if (EPI == EPI_GELU)
          v = 0.5f * v * (1.0f + erff(v * 0.70710678118654752f));
        if (EPI == EPI_F32RES) {
          const size_t idx = (size_t)m * N + n;
          Cf[idx] = v + resf[idx];
        } else {
          Cb[(size_t)m * N + n] = f2b(v);
        }
      }
    }
  }
}

// ---------------- KS = K+S (bf16) and V^T pre-pass. qg row stride 2048 ----------------
// ksg: [bh][kk][64d]; vtg: [bh][d][2048kk]
__global__ __launch_bounds__(256) void ksvt_kernel(const u16* __restrict__ qg,
                                                   const u16* __restrict__ sb,
                                                   u16* __restrict__ ksg,
                                                   u16* __restrict__ vtg) {
  __shared__ u16 T[64 * 72];
  const int bh = blockIdx.y;
  const int b = bh >> 3, h = bh & 7;
  const int kk0 = blockIdx.x * 64;
  const size_t rb = (size_t)b * 2048;
  const size_t base = (size_t)bh * 131072;
  const int row = threadIdx.x >> 2, cb = (threadIdx.x & 3) * 16;
  const u16* kp = qg + (rb + kk0 + row) * 2048 + 512 + h * 64 + cb;
  const u16* sp = sb + (rb + kk0 + row) * 512 + h * 64 + cb;
  const u16x8 k0v = *(const u16x8*)kp;
  const u16x8 k1v = *(const u16x8*)(kp + 8);
  const u16x8 s0v = *(const u16x8*)sp;
  const u16x8 s1v = *(const u16x8*)(sp + 8);
  u16x8 o0, o1;
#pragma unroll
  for (int i = 0; i < 8; i++) {
    o0[i] = f2b(b2f(k0v[i]) + b2f(s0v[i]));
    o1[i] = f2b(b2f(k1v[i]) + b2f(s1v[i]));
  }
  *(u16x8*)(ksg + base + (size_t)(kk0 + row) * 64 + cb) = o0;
  *(u16x8*)(ksg + base + (size_t)(kk0 + row) * 64 + cb + 8) = o1;
  const u16x8 v0v = *(const u16x8*)(kp + 512);
  const u16x8 v1v = *(const u16x8*)(kp + 520);
  *(u16x8*)&T[row * 72 + cb] = v0v;
  *(u16x8*)&T[row * 72 + cb + 8] = v1v;
  __syncthreads();
  u16x8 a0, a1;
#pragma unroll
  for (int i = 0; i < 8; i++) {
    a0[i] = T[(cb + i) * 72 + row];
    a1[i] = T[(cb + 8 + i) * 72 + row];
  }
  *(u16x8*)(vtg + base + (size_t)row * 2048 + kk0 + cb) = a0;
  *(u16x8*)(vtg + base + (size_t)row * 2048 + kk0 + cb + 8) = a1;
}

// ---------------- MFMA flash attention, S^T softmax, XOR-swizzled tiles ----------------
// 64 q/block, wave = 16 q. Epilogue multiplies by gate (qg col 1536+).
__global__ __launch_bounds__(256) void attn_kernel(const u16* __restrict__ qg,
                                                   const u16* __restrict__ ksg,
                                                   const u16* __restrict__ vtg,
                                                   u16* __restrict__ og) {
  __shared__ u16 KSs[64 * 64];
  __shared__ u16 VTs[64 * 64];
  __shared__ u16 PS[4][16 * 72];
  const int tid = threadIdx.x;
  const int w = tid >> 6, lane = tid & 63;
  const int quad = lane >> 4, l16 = lane & 15;
  const int sw = l16 & 7;
  const int q0 = blockIdx.x * 64;
  const int bh = blockIdx.y;
  const int h = bh & 7;
  const size_t rb = (size_t)(bh >> 3) * 2048;
  const size_t base = (size_t)bh * 131072;
  const int lrow = lane >> 3;
  const int lcs = ((lane & 7) ^ lrow) * 8;

  // Q fragments (lane = q row, quad*8 d-offset), scaled 1/8 (exact in bf16)
  s16x8 aq[2];
  {
    const u16* qp = qg + (rb + q0 + w * 16 + l16) * 2048 + h * 64 + quad * 8;
#pragma unroll
    for (int ks = 0; ks < 2; ks++) {
      const u16x8 qv = *(const u16x8*)(qp + ks * 32);
      s16x8 t;
#pragma unroll
      for (int i = 0; i < 8; i++) t[i] = (s16)f2b(b2f(qv[i]) * 0.125f);
      aq[ks] = t;
    }
  }
  float m_run = -1e30f, l_run = 0.f;
  f32x4 oacc[4];
#pragma unroll
  for (int nt = 0; nt < 4; nt++) oacc[nt] = (f32x4){0.f, 0.f, 0.f, 0.f};

  for (int kt = 0; kt < 32; kt++) {
    const int kk0 = kt * 64;
    __syncthreads();
#pragma unroll
    for (int i = 0; i < 2; i++) {
      const int ch = w * 2 + i;
      gld16(ksg + base + (size_t)(kk0 + ch * 8 + lrow) * 64 + lcs, &KSs[ch * 512]);
      gld16(vtg + base + (size_t)(ch * 8 + lrow) * 2048 + kk0 + lcs, &VTs[ch * 512]);
    }
    __syncthreads();
    // S^T[k][q] = KS @ Q^T ; D: col=l16=q, row=quad*4+r=k within mt*16
    f32x4 sacc[4];
#pragma unroll
    for (int mt = 0; mt < 4; mt++) sacc[mt] = (f32x4){0.f, 0.f, 0.f, 0.f};
#pragma unroll
    for (int ks = 0; ks < 2; ks++) {
#pragma unroll
      for (int mt = 0; mt < 4; mt++) {
        const s16x8 kf = *(const s16x8*)&KSs[(mt * 16 + l16) * 64 +
                                             (((ks * 4 + quad) ^ sw) * 8)];
        sacc[mt] = MFMA16(kf, aq[ks], sacc[mt]);
      }
    }
    // online softmax for q=l16 (lane holds 16 distinct k)
    float lm = -1e30f;
#pragma unroll
    for (int mt = 0; mt < 4; mt++)
#pragma unroll
      for (int r = 0; r < 4; r++) lm = fmaxf(lm, sacc[mt][r]);
    lm = fmaxf(lm, __shfl_xor(lm, 16, 64));
    lm = fmaxf(lm, __shfl_xor(lm, 32, 64));
    const float mn = fmaxf(m_run, lm);
    const float alpha = __expf(m_run - mn);
    m_run = mn;
    float ls = 0.f;
#pragma unroll
    for (int mt = 0; mt < 4; mt++) {
#pragma unroll
      for (int r = 0; r < 4; r++) {
        const float pv = __expf(sacc[mt][r] - mn);
        sacc[mt][r] = pv;
        ls += pv;
      }
    }
    ls += __shfl_xor(ls, 16, 64);
    ls += __shfl_xor(ls, 32, 64);
    l_run = l_run * alpha + ls;
    // P store: lane owns q=l16, k = mt*16+quad*4+(0..3) -> b64
#pragma unroll
    for (int mt = 0; mt < 4; mt++) {
      u16x4 pk;
#pragma unroll
      for (int r = 0; r < 4; r++) pk[r] = f2b(sacc[mt][r]);
      *(u16x4*)&PS[w][l16 * 72 + mt * 16 + quad * 4] = pk;
    }
#pragma unroll
    for (int r = 0; r < 4; r++) {
      const float af = __shfl(alpha, quad * 4 + r, 64);
#pragma unroll
      for (int nt = 0; nt < 4; nt++) oacc[nt][r] *= af;
    }
    // O += P @ V
#pragma unroll
    for (int ks = 0; ks < 2; ks++) {
      const s16x8 pf = *(const s16x8*)&PS[w][l16 * 72 + ks * 32 + quad * 8];
#pragma unroll
      for (int nt = 0; nt < 4; nt++) {
        const s16x8 vf = *(const s16x8*)&VTs[(nt * 16 + l16) * 64 +
                                             (((ks * 4 + quad) ^ sw) * 8)];
        oacc[nt] = MFMA16(pf, vf, oacc[nt]);
      }
    }
  }
  // epilogue: o / l * gate
#pragma unroll
  for (int r = 0; r < 4; r++) {
    const float linv = 1.0f / __shfl(l_run, quad * 4 + r, 64);
    const size_t grow = (rb + q0 + w * 16 + quad * 4 + r) * 2048 + 1536 + h * 64;
    const size_t rowb = (rb + q0 + w * 16 + quad * 4 + r) * 512 + h * 64;
#pragma unroll
    for (int nt = 0; nt < 4; nt++) {
      const float g = b2f(qg[grow + nt * 16 + l16]);
      og[rowb + nt * 16 + l16] = f2b(oacc[nt][r] * linv * g);
    }
  }
}

extern "C" void kernel_launch(void* const* d_in, const int* in_sizes, int n_in,
                              void* d_out, int out_size, void* d_ws, size_t ws_size,
                              hipStream_t stream) {
  const float* x      = (const float*)d_in[0];
  const float* e      = (const float*)d_in[1];
  const float* w_qkv  = (const float*)d_in[2];
  const float* w_s    = (const float*)d_in[3];
  const float* w_gate = (const float*)d_in[4];
  const float* w_proj = (const float*)d_in[5];
  const float* b_proj = (const float*)d_in[6];
  const float* ln1w   = (const float*)d_in[7];
  const float* ln1b   = (const float*)d_in[8];
  const float* ln2w   = (const float*)d_in[9];
  const float* ln2b   = (const float*)d_in[10];
  const float* ln3w   = (const float*)d_in[11];
  const float* ln3b   = (const float*)d_in[12];
  const float* w_fc1  = (const float*)d_in[13];
  const float* b_fc1  = (const float*)d_in[14];
  const float* w_fc2  = (const float*)d_in[15];
  const float* b_fc2  = (const float*)d_in[16];
  float* out = (float*)d_out;  // fp32 x1 spine (proj writes, ln3/fc2 read) + final out
  char* ws = (char*)d_ws;

  u16* xn    = (u16*)(ws + 0);         // ln1 out; reused as xn3
  u16* en    = (u16*)(ws + 8388608);   // ln2 out; reused as ksg
  u16* qg    = (u16*)(ws + 16777216);  // 32 MiB [q|k|v|gate] stride 2048; reused as hbuf
  u16* sbuf  = (u16*)(ws + 50331648);  // 8 MiB
  u16* obuf  = (u16*)(ws + 58720256);  // 8 MiB (o*gate, attn out)
  u16* wqgT  = (u16*)(ws + 67108864);  // 2048x512 bf16 (qkv rows 0..1535, gate 1536..2047)
  u16* wsT   = (u16*)(ws + 69206016);  // 512x512
  u16* wpT   = (u16*)(ws + 69730304);  // 512x512
  u16* wf1T  = (u16*)(ws + 70254592);  // 2048x512
  u16* wf2T  = (u16*)(ws + 72351744);  // 512x2048
  u16* vtg   = (u16*)(ws + 74448896);  // 8 MiB V^T
  u16* ksg   = en;
  u16* hbuf  = qg;
  u16* xn3   = xn;

  dim3 blk(256);
  wprep_kernel<<<896, blk, 0, stream>>>(w_qkv, w_s, w_gate, w_proj, w_fc1, w_fc2,
                                        wqgT, wsT, wpT, wf1T, wf2T);
  ln12_kernel<<<4096, blk, 0, stream>>>(x, e, ln1w, ln1b, ln2w, ln2b, xn, en);
  mgemm<EPI_NONE, 128><<<dim3(16, 64), blk, 0, stream>>>(
      xn, wqgT, 8192, 2048, 512, qg, nullptr, nullptr, nullptr);
  mgemm<EPI_NONE, 64><<<dim3(4, 128), blk, 0, stream>>>(
      en, wsT, 8192, 512, 512, sbuf, nullptr, nullptr, nullptr);
  ksvt_kernel<<<dim3(32, 32), blk, 0, stream>>>(qg, sbuf, ksg, vtg);
  attn_kernel<<<dim3(32, 32), blk, 0, stream>>>(qg, ksg, vtg, obuf);
  mgemm<EPI_F32RES, 64><<<dim3(4, 128), blk, 0, stream>>>(
      obuf, wpT, 8192, 512, 512, nullptr, out, b_proj, x);
  ln_kernel<<<2048, blk, 0, stream>>>(out, ln3w, ln3b, xn3);
  mgemm<EPI_GELU, 128><<<dim3(16, 64), blk, 0, stream>>>(
      xn3, wf1T, 8192, 2048, 512, hbuf, nullptr, b_fc1, nullptr);
  mgemm<EPI_F32RES, 64><<<dim3(4, 128), blk, 0, stream>>>(
      hbuf, wf2T, 8192, 512, 2048, nullptr, out, b_fc2, out);
  (void)in_sizes; (void)n_in; (void)out_size; (void)ws_size;
}